// Round 3
// baseline (1324.885 us; speedup 1.0000x reference)
//
#include <hip/hip_runtime.h>

// DeltanetHead: T=4096, B=8, C=1024, F=128
// R6: defeat SMEM scalarization of the c/s prefetch stream.
// Evidence R3-R5: cyc/step pinned at ~530 regardless of ring depth, and
// VGPR_Count (56/76/80) always < ring footprint (96) while SGPR=112.
// Diagnosis: Pc/Ps loads are lane-UNIFORM (address = Pt+256+r0, no lane
// term), so LLVM scalarizes them to s_load -> SGPRs. SMEM returns
// OUT-OF-ORDER, so consuming any s_load result forces lgkmcnt(0), which
// drains the s_loads issued in the previous step -> ~400 cyc scalar-cache
// latency exposed EVERY step, independent of the VMEM prefetch ring.
// Fix: launder the c/s pointers through an empty asm with "+v" constraint;
// asm outputs are divergent, so the loads become global_load (VMEM,
// in-order vmcnt) and the whole 96-reg ring stays vector-resident.

#define T_DIM 4096
#define B_DIM 8
#define C_DIM 1024
#define F_DIM 128

typedef __attribute__((ext_vector_type(8))) short bf16x8;
typedef __attribute__((ext_vector_type(4))) float f32x4;

__device__ __forceinline__ unsigned short f2bf(float f) {
  unsigned u = __float_as_uint(f);
  u += 0x7fffu + ((u >> 16) & 1u);   // round-to-nearest-even
  return (unsigned short)(u >> 16);
}
__device__ __forceinline__ float bfu2f(unsigned u) { return __uint_as_float(u << 16); }

// ---------------- elementwise fp32 -> bf16 convert (vectorized x4) ----------------
__global__ void cvt_kernel(const float* __restrict__ in, unsigned short* __restrict__ out, int n4) {
  int i = blockIdx.x * blockDim.x + threadIdx.x;
  int stride = gridDim.x * blockDim.x;
  for (; i < n4; i += stride) {
    float4 v = ((const float4*)in)[i];
    ushort4 r;
    r.x = f2bf(v.x); r.y = f2bf(v.y); r.z = f2bf(v.z); r.w = f2bf(v.w);
    ((ushort4*)out)[i] = r;
  }
}

// ---------------- pack 6 [F][C] weights -> Wall[768][1024] bf16 + bias[768] ----------------
__global__ void pack_w_kernel(const float* __restrict__ Aw, const float* __restrict__ Ab,
                              const float* __restrict__ Bw, const float* __restrict__ Bb,
                              const float* __restrict__ Cw, const float* __restrict__ Cb,
                              const float* __restrict__ Dw, const float* __restrict__ Db,
                              const float* __restrict__ Iw, const float* __restrict__ Ib,
                              const float* __restrict__ Sw, const float* __restrict__ Sb,
                              unsigned short* __restrict__ Wall, float* __restrict__ biasAll) {
  const float scaleB = 0.08838834764831845f;  // 1/sqrt(128), folded into b-projection
  int idx = blockIdx.x * 256 + threadIdx.x;
  if (idx < 768 * 1024) {
    int row = idx >> 10, c = idx & 1023;
    int slot = row >> 7, rr = row & 127;
    const float* W = slot == 0 ? Aw : slot == 1 ? Bw : slot == 2 ? Cw
                   : slot == 3 ? Dw : slot == 4 ? Iw : Sw;
    float v = W[rr * 1024 + c];
    if (slot == 1) v *= scaleB;
    Wall[idx] = f2bf(v);
  }
  if (idx < 768) {
    int slot = idx >> 7, rr = idx & 127;
    const float* Bv = slot == 0 ? Ab : slot == 1 ? Bb : slot == 2 ? Cb
                    : slot == 3 ? Db : slot == 4 ? Ib : Sb;
    float v = Bv[rr];
    if (slot == 1) v *= scaleB;
    biasAll[idx] = v;
  }
}

// ---------------- bf16 MFMA GEMM: C[M][N] = A[M][K] * B[N][K]^T (+bias, +sigmoid range) ----------------
__global__ __launch_bounds__(256) void gemm_bt(
    const unsigned short* __restrict__ A,
    const unsigned short* __restrict__ Bm,
    float* __restrict__ Cm,
    const float* __restrict__ bias,
    int M, int N, int K, int sig_lo, int sig_hi) {
  __shared__ unsigned short As[128 * 32];
  __shared__ unsigned short Bs[128 * 32];
  const int tid = threadIdx.x;
  const int m0 = blockIdx.x * 128;
  const int n0 = blockIdx.y * 128;
  const int wv = tid >> 6, ln = tid & 63;
  const int mo = (wv & 1) * 64, no = (wv >> 1) * 64;
  const int lrow = ln & 15, lq = ln >> 4;
  f32x4 acc[4][4] = {};

  for (int kt = 0; kt < K; kt += 32) {
#pragma unroll
    for (int it = 0; it < 2; ++it) {
      int idx = it * 256 + tid;
      int row = idx >> 2, kc = idx & 3;
      *(int4*)&As[row * 32 + kc * 8] = *(const int4*)&A[(size_t)(m0 + row) * K + kt + kc * 8];
      *(int4*)&Bs[row * 32 + kc * 8] = *(const int4*)&Bm[(size_t)(n0 + row) * K + kt + kc * 8];
    }
    __syncthreads();
    bf16x8 af[4], bf[4];
#pragma unroll
    for (int i = 0; i < 4; ++i) {
      af[i] = *(const bf16x8*)&As[(mo + i * 16 + lrow) * 32 + lq * 8];
      bf[i] = *(const bf16x8*)&Bs[(no + i * 16 + lrow) * 32 + lq * 8];
    }
#pragma unroll
    for (int i = 0; i < 4; ++i)
#pragma unroll
      for (int j = 0; j < 4; ++j)
        acc[i][j] = __builtin_amdgcn_mfma_f32_16x16x32_bf16(af[i], bf[j], acc[i][j], 0, 0, 0);
    __syncthreads();
  }

#pragma unroll
  for (int i = 0; i < 4; ++i) {
#pragma unroll
    for (int j = 0; j < 4; ++j) {
      int col = n0 + no + j * 16 + lrow;
      float bv = bias ? bias[col] : 0.0f;
      bool sig = (col >= sig_lo) && (col < sig_hi);
#pragma unroll
      for (int r = 0; r < 4; ++r) {
        int row = m0 + mo + i * 16 + lq * 4 + r;
        float v = acc[i][j][r] + bv;
        if (sig) v = 1.0f / (1.0f + __expf(-v));
        Cm[(size_t)row * N + col] = v;
      }
    }
  }
}

// ---------------- wave-wide sum via DPP ----------------
__device__ __forceinline__ float wave_sum64(float x) {
  x += __int_as_float(__builtin_amdgcn_update_dpp(0, __float_as_int(x), 0x111, 0xf, 0xf, false)); // row_shr:1
  x += __int_as_float(__builtin_amdgcn_update_dpp(0, __float_as_int(x), 0x112, 0xf, 0xf, false)); // row_shr:2
  x += __int_as_float(__builtin_amdgcn_update_dpp(0, __float_as_int(x), 0x114, 0xf, 0xf, false)); // row_shr:4
  x += __int_as_float(__builtin_amdgcn_update_dpp(0, __float_as_int(x), 0x118, 0xf, 0xf, false)); // row_shr:8
  x += __int_as_float(__builtin_amdgcn_update_dpp(0, __float_as_int(x), 0x142, 0xf, 0xf, false)); // row_bcast:15
  x += __int_as_float(__builtin_amdgcn_update_dpp(0, __float_as_int(x), 0x143, 0xf, 0xf, false)); // row_bcast:31
  return __int_as_float(__builtin_amdgcn_readlane(__float_as_int(x), 63));
}

// ---------------- sequential scan ----------------
// grid (B, G), 256 thr (4 waves). Wave owns ROWS rows, lane owns 2 cols.
// 8-slot ALL-VGPR prefetch ring (c/s pointers laundered through asm so
// they cannot be scalarized to out-of-order SMEM). LDS cross-wave reduce
// once per 8 steps behind a lgkmcnt-only barrier (parity double-buffered)
// so the vmem ring is never drained in-loop.
template <int ROWS>
__global__ __launch_bounds__(256, 1) void scan_kernel(
    const float* __restrict__ P,          // [T][B][6][128] fp32
    const float* __restrict__ state_in,   // [B][128][128]
    unsigned short* __restrict__ o_part,  // [G][T][B][128] bf16
    float* __restrict__ state_out) {      // [B][128][128]
  const int b = blockIdx.x;
  const int gq = blockIdx.y;
  const int wave = threadIdx.x >> 6;
  const int lane = threadIdx.x & 63;
  const int r0 = gq * (4 * ROWS) + wave * ROWS;
  const int j0 = lane * 2;
  __shared__ float buf[2][4][8][128];   // [parity][wave][step-in-batch][col] = 32 KB

  float2 st[ROWS];
#pragma unroll
  for (int r = 0; r < ROWS; ++r)
    st[r] = *(const float2*)&state_in[((size_t)b * F_DIM + r0 + r) * F_DIM + j0];

  // 8-slot prefetch ring (distance-8; tail prefetches overrun past P's end
  // into the adjacent allocated ob region and are never consumed)
  float2 Pa[8], Pb[8], Pd[8], Pg[8];
  float Pc[8][ROWS], Ps[8][ROWS];
  const size_t PSTEP = (size_t)B_DIM * 768;
  const float* P0 = P + (size_t)b * 768;

#define RING_LOAD(sl, Pt)                                                   \
  do {                                                                      \
    Pa[sl] = *(const float2*)((Pt) + 0 + j0);                               \
    Pb[sl] = *(const float2*)((Pt) + 128 + j0);                             \
    Pd[sl] = *(const float2*)((Pt) + 384 + j0);                             \
    Pg[sl] = *(const float2*)((Pt) + 512 + j0);                             \
    /* c/s addresses are lane-uniform; launder through a VGPR so the     */ \
    /* loads stay VMEM (global_load, in-order vmcnt) instead of SMEM     */ \
    const float* pc_ = (Pt) + 256 + r0;                                     \
    const float* ps_ = (Pt) + 640 + r0;                                     \
    asm("" : "+v"(pc_), "+v"(ps_));                                         \
    if constexpr (ROWS == 2) {                                              \
      float2 v_ = *(const float2*)pc_;                                      \
      Pc[sl][0] = v_.x; Pc[sl][1] = v_.y;                                   \
      float2 w_ = *(const float2*)ps_;                                      \
      Ps[sl][0] = w_.x; Ps[sl][1] = w_.y;                                   \
    } else {                                                                \
      float4 v_ = *(const float4*)pc_;                                      \
      Pc[sl][0] = v_.x; Pc[sl][1] = v_.y; Pc[sl][2] = v_.z; Pc[sl][3] = v_.w; \
      float4 w_ = *(const float4*)ps_;                                      \
      Ps[sl][0] = w_.x; Ps[sl][1] = w_.y; Ps[sl][2] = w_.z; Ps[sl][3] = w_.w; \
    }                                                                       \
  } while (0)

#pragma unroll
  for (int k = 0; k < 8; ++k) RING_LOAD(k, P0 + (size_t)k * PSTEP);

  for (int t8 = 0; t8 < T_DIM; t8 += 8) {
    const int pb = (t8 >> 3) & 1;
#pragma unroll
    for (int k = 0; k < 8; ++k) {
      // grab current step's values (SSA copies; regalloc coalesces)
      float2 a2 = Pa[k], b2 = Pb[k], d2 = Pd[k], g2 = Pg[k];
      float cc[ROWS], ss[ROWS];
#pragma unroll
      for (int r = 0; r < ROWS; ++r) { cc[r] = Pc[k][r]; ss[r] = Ps[k][r]; }

      // issue prefetch for step t+8 into this slot (off the dependency chain)
      const float* Pn = P0 + (size_t)(t8 + k + 8) * PSTEP;
      RING_LOAD(k, Pn);

      // v[r] = st[r,:] . a  (old state, wave-wide reduce over 128 cols)
      float vr[ROWS];
#pragma unroll
      for (int r = 0; r < ROWS; ++r)
        vr[r] = wave_sum64(st[r].x * a2.x + st[r].y * a2.y);

      // st update + partial out over this wave's rows
      float ox = 0.0f, oy = 0.0f;
#pragma unroll
      for (int r = 0; r < ROWS; ++r) {
        st[r].x = st[r].x * g2.x + vr[r] * b2.x + cc[r] * d2.x;
        st[r].y = st[r].y * g2.y + vr[r] * b2.y + cc[r] * d2.y;
        ox += ss[r] * st[r].x;
        oy += ss[r] * st[r].y;
      }
      *(float2*)&buf[pb][wave][k][j0] = make_float2(ox, oy);
      // pin this step's region: the slot-(t+8) loads above may not sink
      // into later steps; later compute may not hoist above.
      __builtin_amdgcn_sched_barrier(0);
    }
    // LDS-only barrier: orders the buf writes without draining the vmem
    // prefetch ring (__syncthreads would emit s_waitcnt vmcnt(0)).
    asm volatile("s_waitcnt lgkmcnt(0)" ::: "memory");
    __builtin_amdgcn_s_barrier();
    asm volatile("" ::: "memory");

    // cross-wave reduce of the 8-step batch: 512 items = 8 steps x 64 col-pairs
#pragma unroll
    for (int h = 0; h < 2; ++h) {
      int it = threadIdx.x + h * 256;
      int k = it >> 6, c2 = (it & 63) * 2;
      float2 s0 = *(const float2*)&buf[pb][0][k][c2];
      float2 s1 = *(const float2*)&buf[pb][1][k][c2];
      float2 s2 = *(const float2*)&buf[pb][2][k][c2];
      float2 s3 = *(const float2*)&buf[pb][3][k][c2];
      float sx = s0.x + s1.x + s2.x + s3.x;
      float sy = s0.y + s1.y + s2.y + s3.y;
      unsigned pk = (unsigned)f2bf(sx) | ((unsigned)f2bf(sy) << 16);
      *(unsigned*)&o_part[(((size_t)gq * T_DIM + t8 + k) * B_DIM + b) * F_DIM + c2] = pk;
    }
    // no second barrier: parity double-buffer + the next batch's barrier orders reuse
  }
#undef RING_LOAD

#pragma unroll
  for (int r = 0; r < ROWS; ++r)
    *(float2*)&state_out[((size_t)b * F_DIM + r0 + r) * F_DIM + j0] = st[r];
}

// ---------------- sum G bf16 partials -> ob bf16 (memory-bound) ----------------
__global__ void reduce_kernel(const unsigned short* __restrict__ o_part,
                              unsigned short* __restrict__ ob, int G) {
  const size_t NEL = (size_t)T_DIM * B_DIM * F_DIM;  // 4,194,304
  size_t i = ((size_t)blockIdx.x * 256 + threadIdx.x) * 8;
  if (i >= NEL) return;
  float acc[8] = {0, 0, 0, 0, 0, 0, 0, 0};
  for (int g = 0; g < G; ++g) {
    int4 v = *(const int4*)(o_part + (size_t)g * NEL + i);
    unsigned w0 = (unsigned)v.x, w1 = (unsigned)v.y, w2 = (unsigned)v.z, w3 = (unsigned)v.w;
    acc[0] += bfu2f(w0 & 0xffffu); acc[1] += bfu2f(w0 >> 16);
    acc[2] += bfu2f(w1 & 0xffffu); acc[3] += bfu2f(w1 >> 16);
    acc[4] += bfu2f(w2 & 0xffffu); acc[5] += bfu2f(w2 >> 16);
    acc[6] += bfu2f(w3 & 0xffffu); acc[7] += bfu2f(w3 >> 16);
  }
  int4 o;
  o.x = (int)((unsigned)f2bf(acc[0]) | ((unsigned)f2bf(acc[1]) << 16));
  o.y = (int)((unsigned)f2bf(acc[2]) | ((unsigned)f2bf(acc[3]) << 16));
  o.z = (int)((unsigned)f2bf(acc[4]) | ((unsigned)f2bf(acc[5]) << 16));
  o.w = (int)((unsigned)f2bf(acc[6]) | ((unsigned)f2bf(acc[7]) << 16));
  *(int4*)(ob + i) = o;
}

extern "C" void kernel_launch(void* const* d_in, const int* in_sizes, int n_in,
                              void* d_out, int out_size, void* d_ws, size_t ws_size,
                              hipStream_t stream) {
  const float* x  = (const float*)d_in[0];
  const float* st = (const float*)d_in[1];
  const float* Aw = (const float*)d_in[2];
  const float* Ab = (const float*)d_in[3];
  const float* Bw = (const float*)d_in[4];
  const float* Bb = (const float*)d_in[5];
  const float* Cw = (const float*)d_in[6];
  const float* Cb = (const float*)d_in[7];
  const float* Dw = (const float*)d_in[8];
  const float* Db = (const float*)d_in[9];
  const float* Iw = (const float*)d_in[10];
  const float* Ib = (const float*)d_in[11];
  const float* Sw = (const float*)d_in[12];
  const float* Sb = (const float*)d_in[13];
  const float* Ow = (const float*)d_in[14];

  float* y = (float*)d_out;                               // [T][B][C]
  float* state_out = y + (size_t)T_DIM * B_DIM * C_DIM;   // [B][F][F]

  // workspace carve:
  //   Wall      @ 0           (1,572,864)
  //   biasAll   @ 1,572,864   (3,072, padded)
  //   Owb       @ 1,576,960   (262,144)
  //   P         @ 1,839,104   (100,663,296)
  //   ob        @ 102,502,400 (8,388,608)
  //   xb        @ 110,891,008 (67,108,864)  -- dead after proj GEMM
  //   o_part    @ 110,891,008 (G * 8,388,608) reuses xb region; G=16 extends past it
  char* ws = (char*)d_ws;
  unsigned short* Wall = (unsigned short*)(ws);
  float* biasAll       = (float*)(ws + 1572864);
  unsigned short* Owb  = (unsigned short*)(ws + 1576960);
  float* P             = (float*)(ws + 1839104);
  unsigned short* ob   = (unsigned short*)(ws + 102502400);
  unsigned short* xb   = (unsigned short*)(ws + 110891008);
  unsigned short* o_part = xb;

  // G=16 wants 110,891,008 + 16*8,388,608 = 245,108,736 bytes of ws
  const int G = (ws_size >= 245108736u) ? 16 : 8;

  cvt_kernel<<<4096, 256, 0, stream>>>(x, xb, 33554432 / 4);
  pack_w_kernel<<<3072, 256, 0, stream>>>(Aw, Ab, Bw, Bb, Cw, Cb, Dw, Db, Iw, Ib, Sw, Sb,
                                          Wall, biasAll);
  cvt_kernel<<<128, 256, 0, stream>>>(Ow, Owb, 131072 / 4);
  // projections: P = x @ Wall^T + bias, sigmoid on I-slot cols [512,640)
  gemm_bt<<<dim3(256, 6), 256, 0, stream>>>(xb, Wall, P, biasAll, 32768, 768, 1024, 512, 640);
  if (G == 16)
    scan_kernel<2><<<dim3(8, 16), 256, 0, stream>>>(P, st, o_part, state_out);
  else
    scan_kernel<4><<<dim3(8, 8), 256, 0, stream>>>(P, st, o_part, state_out);
  reduce_kernel<<<2048, 256, 0, stream>>>(o_part, ob, G);
  // y = o @ O_w^T
  gemm_bt<<<dim3(256, 8), 256, 0, stream>>>(ob, Owb, y, nullptr, 32768, 1024, 128, 0, 0);
}

// Round 4
// 1136.168 us; speedup vs baseline: 1.1661x; 1.1661x over previous
//
#include <hip/hip_runtime.h>

// DeltanetHead: T=4096, B=8, C=1024, F=128
// R7: feed the scan through LDS. Evidence R3-R6: cyc/step pinned at ~530
// across four global-prefetch structures; VGPR_Count (56/76/80) always <
// ring footprint (96); no scratch traffic => hipcc sinks the ring loads to
// their uses (effective prefetch distance 0) and every step exposes L2/L3
// latency on the serial chain. Per the guide (m97/m201), the async path the
// compiler does NOT mangle is global_load_lds staging with per-batch waits:
//   - per 8-step batch, 4 waves DMA the next batch's 24KB of P into LDS
//     (6 x global_load_lds width-16 per wave), waited ONCE per batch at the
//     existing barrier (issued ~1600cyc earlier => free);
//   - per step, operands come from LDS (ds_read_b64, conflict-free) with a
//     1-step register prefetch (12 VGPR - small enough to stay resident).

#define T_DIM 4096
#define B_DIM 8
#define C_DIM 1024
#define F_DIM 128

typedef __attribute__((ext_vector_type(8))) short bf16x8;
typedef __attribute__((ext_vector_type(4))) float f32x4;

__device__ __forceinline__ unsigned short f2bf(float f) {
  unsigned u = __float_as_uint(f);
  u += 0x7fffu + ((u >> 16) & 1u);   // round-to-nearest-even
  return (unsigned short)(u >> 16);
}
__device__ __forceinline__ float bfu2f(unsigned u) { return __uint_as_float(u << 16); }

__device__ __forceinline__ void gload_lds16(const float* g, float* l) {
  __builtin_amdgcn_global_load_lds((const __attribute__((address_space(1))) void*)g,
                                   (__attribute__((address_space(3))) void*)l, 16, 0, 0);
}

// ---------------- elementwise fp32 -> bf16 convert (vectorized x4) ----------------
__global__ void cvt_kernel(const float* __restrict__ in, unsigned short* __restrict__ out, int n4) {
  int i = blockIdx.x * blockDim.x + threadIdx.x;
  int stride = gridDim.x * blockDim.x;
  for (; i < n4; i += stride) {
    float4 v = ((const float4*)in)[i];
    ushort4 r;
    r.x = f2bf(v.x); r.y = f2bf(v.y); r.z = f2bf(v.z); r.w = f2bf(v.w);
    ((ushort4*)out)[i] = r;
  }
}

// ---------------- pack 6 [F][C] weights -> Wall[768][1024] bf16 + bias[768] ----------------
__global__ void pack_w_kernel(const float* __restrict__ Aw, const float* __restrict__ Ab,
                              const float* __restrict__ Bw, const float* __restrict__ Bb,
                              const float* __restrict__ Cw, const float* __restrict__ Cb,
                              const float* __restrict__ Dw, const float* __restrict__ Db,
                              const float* __restrict__ Iw, const float* __restrict__ Ib,
                              const float* __restrict__ Sw, const float* __restrict__ Sb,
                              unsigned short* __restrict__ Wall, float* __restrict__ biasAll) {
  const float scaleB = 0.08838834764831845f;  // 1/sqrt(128), folded into b-projection
  int idx = blockIdx.x * 256 + threadIdx.x;
  if (idx < 768 * 1024) {
    int row = idx >> 10, c = idx & 1023;
    int slot = row >> 7, rr = row & 127;
    const float* W = slot == 0 ? Aw : slot == 1 ? Bw : slot == 2 ? Cw
                   : slot == 3 ? Dw : slot == 4 ? Iw : Sw;
    float v = W[rr * 1024 + c];
    if (slot == 1) v *= scaleB;
    Wall[idx] = f2bf(v);
  }
  if (idx < 768) {
    int slot = idx >> 7, rr = idx & 127;
    const float* Bv = slot == 0 ? Ab : slot == 1 ? Bb : slot == 2 ? Cb
                    : slot == 3 ? Db : slot == 4 ? Ib : Sb;
    float v = Bv[rr];
    if (slot == 1) v *= scaleB;
    biasAll[idx] = v;
  }
}

// ---------------- bf16 MFMA GEMM: C[M][N] = A[M][K] * B[N][K]^T (+bias, +sigmoid range) ----------------
__global__ __launch_bounds__(256) void gemm_bt(
    const unsigned short* __restrict__ A,
    const unsigned short* __restrict__ Bm,
    float* __restrict__ Cm,
    const float* __restrict__ bias,
    int M, int N, int K, int sig_lo, int sig_hi) {
  __shared__ unsigned short As[128 * 32];
  __shared__ unsigned short Bs[128 * 32];
  const int tid = threadIdx.x;
  const int m0 = blockIdx.x * 128;
  const int n0 = blockIdx.y * 128;
  const int wv = tid >> 6, ln = tid & 63;
  const int mo = (wv & 1) * 64, no = (wv >> 1) * 64;
  const int lrow = ln & 15, lq = ln >> 4;
  f32x4 acc[4][4] = {};

  for (int kt = 0; kt < K; kt += 32) {
#pragma unroll
    for (int it = 0; it < 2; ++it) {
      int idx = it * 256 + tid;
      int row = idx >> 2, kc = idx & 3;
      *(int4*)&As[row * 32 + kc * 8] = *(const int4*)&A[(size_t)(m0 + row) * K + kt + kc * 8];
      *(int4*)&Bs[row * 32 + kc * 8] = *(const int4*)&Bm[(size_t)(n0 + row) * K + kt + kc * 8];
    }
    __syncthreads();
    bf16x8 af[4], bf[4];
#pragma unroll
    for (int i = 0; i < 4; ++i) {
      af[i] = *(const bf16x8*)&As[(mo + i * 16 + lrow) * 32 + lq * 8];
      bf[i] = *(const bf16x8*)&Bs[(no + i * 16 + lrow) * 32 + lq * 8];
    }
#pragma unroll
    for (int i = 0; i < 4; ++i)
#pragma unroll
      for (int j = 0; j < 4; ++j)
        acc[i][j] = __builtin_amdgcn_mfma_f32_16x16x32_bf16(af[i], bf[j], acc[i][j], 0, 0, 0);
    __syncthreads();
  }

#pragma unroll
  for (int i = 0; i < 4; ++i) {
#pragma unroll
    for (int j = 0; j < 4; ++j) {
      int col = n0 + no + j * 16 + lrow;
      float bv = bias ? bias[col] : 0.0f;
      bool sig = (col >= sig_lo) && (col < sig_hi);
#pragma unroll
      for (int r = 0; r < 4; ++r) {
        int row = m0 + mo + i * 16 + lq * 4 + r;
        float v = acc[i][j][r] + bv;
        if (sig) v = 1.0f / (1.0f + __expf(-v));
        Cm[(size_t)row * N + col] = v;
      }
    }
  }
}

// ---------------- wave-wide sum via DPP ----------------
__device__ __forceinline__ float wave_sum64(float x) {
  x += __int_as_float(__builtin_amdgcn_update_dpp(0, __float_as_int(x), 0x111, 0xf, 0xf, false)); // row_shr:1
  x += __int_as_float(__builtin_amdgcn_update_dpp(0, __float_as_int(x), 0x112, 0xf, 0xf, false)); // row_shr:2
  x += __int_as_float(__builtin_amdgcn_update_dpp(0, __float_as_int(x), 0x114, 0xf, 0xf, false)); // row_shr:4
  x += __int_as_float(__builtin_amdgcn_update_dpp(0, __float_as_int(x), 0x118, 0xf, 0xf, false)); // row_shr:8
  x += __int_as_float(__builtin_amdgcn_update_dpp(0, __float_as_int(x), 0x142, 0xf, 0xf, false)); // row_bcast:15
  x += __int_as_float(__builtin_amdgcn_update_dpp(0, __float_as_int(x), 0x143, 0xf, 0xf, false)); // row_bcast:31
  return __int_as_float(__builtin_amdgcn_readlane(__float_as_int(x), 63));
}

// ---------------- sequential scan ----------------
// grid (B, G), 256 thr (4 waves). Wave owns ROWS rows, lane owns 2 cols.
// P is staged batch-by-batch into LDS via global_load_lds (double-buffered,
// waited once per batch); per-step reads are ds_read from LDS with a 1-step
// register prefetch. Cross-wave reduce once per 8 steps (parity dbuf).
template <int ROWS>
__global__ __launch_bounds__(256, 1) void scan_kernel(
    const float* __restrict__ P,          // [T][B][6][128] fp32
    const float* __restrict__ state_in,   // [B][128][128]
    unsigned short* __restrict__ o_part,  // [G][T][B][128] bf16
    float* __restrict__ state_out) {      // [B][128][128]
  const int b = blockIdx.x;
  const int gq = blockIdx.y;
  const int wave = threadIdx.x >> 6;
  const int lane = threadIdx.x & 63;
  const int r0 = gq * (4 * ROWS) + wave * ROWS;
  const int j0 = lane * 2;
  __shared__ float stage[2][8][768];    // 48 KB: [buf][step][768] P rows
  __shared__ float buf[2][4][8][128];   // 32 KB: [parity][wave][step][col]

  float2 st[ROWS];
#pragma unroll
  for (int r = 0; r < ROWS; ++r)
    st[r] = *(const float2*)&state_in[((size_t)b * F_DIM + r0 + r) * F_DIM + j0];

  // stage one 8-step batch starting at time tstart into stage[sb]:
  // 24 chunks of 1024B (3 per step); wave w stages steps {2w, 2w+1}.
  // tail batch overruns past P's end into the adjacent allocated ob region
  // (staged but never consumed).
  auto stage_batch = [&](int sb, int tstart) {
#pragma unroll
    for (int c6 = 0; c6 < 6; ++c6) {
      int tl = wave * 2 + (c6 >= 3 ? 1 : 0);
      int part = c6 - (c6 >= 3 ? 3 : 0);
      const float* g = P + ((size_t)(tstart + tl) * B_DIM + b) * 768 + part * 256 + lane * 4;
      gload_lds16(g, &stage[sb][tl][part * 256]);
    }
  };

#define LDS_STEP(da, db, dd, dg, dc, ds, sb, kk)                             \
  do {                                                                       \
    const float* Sp = &stage[sb][kk][0];                                     \
    da = *(const float2*)(Sp + 0 + j0);                                      \
    db = *(const float2*)(Sp + 128 + j0);                                    \
    dd = *(const float2*)(Sp + 384 + j0);                                    \
    dg = *(const float2*)(Sp + 512 + j0);                                    \
    if constexpr (ROWS == 2) {                                               \
      float2 v_ = *(const float2*)(Sp + 256 + r0);                           \
      dc[0] = v_.x; dc[1] = v_.y;                                            \
      float2 w_ = *(const float2*)(Sp + 640 + r0);                           \
      ds[0] = w_.x; ds[1] = w_.y;                                            \
    } else {                                                                 \
      float4 v_ = *(const float4*)(Sp + 256 + r0);                           \
      dc[0] = v_.x; dc[1] = v_.y; dc[2] = v_.z; dc[3] = v_.w;                \
      float4 w_ = *(const float4*)(Sp + 640 + r0);                           \
      ds[0] = w_.x; ds[1] = w_.y; ds[2] = w_.z; ds[3] = w_.w;                \
    }                                                                        \
  } while (0)

  // prologue: stage batch 0, wait, sync
  stage_batch(0, 0);
  asm volatile("s_waitcnt vmcnt(0)" ::: "memory");
  __builtin_amdgcn_s_barrier();
  asm volatile("" ::: "memory");

  int cur = 0;
  for (int t8 = 0; t8 < T_DIM; t8 += 8) {
    const int pb = (t8 >> 3) & 1;
    // issue DMA for the next batch into the other stage buffer (waited at
    // this batch's end-of-batch vmcnt(0) -- ~1600 cycles of slack)
    stage_batch(cur ^ 1, t8 + 8);

    // 1-step register prefetch out of LDS
    float2 a2, b2, d2, g2;
    float cc[ROWS], ss[ROWS];
    LDS_STEP(a2, b2, d2, g2, cc, ss, cur, 0);

#pragma unroll
    for (int k = 0; k < 8; ++k) {
      float2 ca = a2, cb = b2, cd = d2, cg = g2;
      float lc[ROWS], ls[ROWS];
#pragma unroll
      for (int r = 0; r < ROWS; ++r) { lc[r] = cc[r]; ls[r] = ss[r]; }
      if (k < 7) LDS_STEP(a2, b2, d2, g2, cc, ss, cur, k + 1);

      // v[r] = st[r,:] . a  (old state, wave-wide reduce over 128 cols)
      float vr[ROWS];
#pragma unroll
      for (int r = 0; r < ROWS; ++r)
        vr[r] = wave_sum64(st[r].x * ca.x + st[r].y * ca.y);

      // st update + partial out over this wave's rows
      float ox = 0.0f, oy = 0.0f;
#pragma unroll
      for (int r = 0; r < ROWS; ++r) {
        st[r].x = st[r].x * cg.x + vr[r] * cb.x + lc[r] * cd.x;
        st[r].y = st[r].y * cg.y + vr[r] * cb.y + lc[r] * cd.y;
        ox += ls[r] * st[r].x;
        oy += ls[r] * st[r].y;
      }
      *(float2*)&buf[pb][wave][k][j0] = make_float2(ox, oy);
      // keep the k+1 LDS reads inside this step's region
      __builtin_amdgcn_sched_barrier(0);
    }

    // end-of-batch: wait staging DMA (vmcnt) + all LDS ops (lgkm), sync.
    asm volatile("s_waitcnt vmcnt(0) lgkmcnt(0)" ::: "memory");
    __builtin_amdgcn_s_barrier();
    asm volatile("" ::: "memory");

    // cross-wave reduce of the 8-step batch: 512 items = 8 steps x 64 col-pairs
#pragma unroll
    for (int h = 0; h < 2; ++h) {
      int it = threadIdx.x + h * 256;
      int k = it >> 6, c2 = (it & 63) * 2;
      float2 s0 = *(const float2*)&buf[pb][0][k][c2];
      float2 s1 = *(const float2*)&buf[pb][1][k][c2];
      float2 s2 = *(const float2*)&buf[pb][2][k][c2];
      float2 s3 = *(const float2*)&buf[pb][3][k][c2];
      float sx = s0.x + s1.x + s2.x + s3.x;
      float sy = s0.y + s1.y + s2.y + s3.y;
      unsigned pk = (unsigned)f2bf(sx) | ((unsigned)f2bf(sy) << 16);
      *(unsigned*)&o_part[(((size_t)gq * T_DIM + t8 + k) * B_DIM + b) * F_DIM + c2] = pk;
    }
    // no second barrier: parity double-buffer + the next batch's barrier
    // orders buf reuse; stage reuse is ordered by the lgkmcnt(0)+barrier.
    cur ^= 1;
  }
#undef LDS_STEP

#pragma unroll
  for (int r = 0; r < ROWS; ++r)
    *(float2*)&state_out[((size_t)b * F_DIM + r0 + r) * F_DIM + j0] = st[r];
}

// ---------------- sum G bf16 partials -> ob bf16 (memory-bound) ----------------
__global__ void reduce_kernel(const unsigned short* __restrict__ o_part,
                              unsigned short* __restrict__ ob, int G) {
  const size_t NEL = (size_t)T_DIM * B_DIM * F_DIM;  // 4,194,304
  size_t i = ((size_t)blockIdx.x * 256 + threadIdx.x) * 8;
  if (i >= NEL) return;
  float acc[8] = {0, 0, 0, 0, 0, 0, 0, 0};
  for (int g = 0; g < G; ++g) {
    int4 v = *(const int4*)(o_part + (size_t)g * NEL + i);
    unsigned w0 = (unsigned)v.x, w1 = (unsigned)v.y, w2 = (unsigned)v.z, w3 = (unsigned)v.w;
    acc[0] += bfu2f(w0 & 0xffffu); acc[1] += bfu2f(w0 >> 16);
    acc[2] += bfu2f(w1 & 0xffffu); acc[3] += bfu2f(w1 >> 16);
    acc[4] += bfu2f(w2 & 0xffffu); acc[5] += bfu2f(w2 >> 16);
    acc[6] += bfu2f(w3 & 0xffffu); acc[7] += bfu2f(w3 >> 16);
  }
  int4 o;
  o.x = (int)((unsigned)f2bf(acc[0]) | ((unsigned)f2bf(acc[1]) << 16));
  o.y = (int)((unsigned)f2bf(acc[2]) | ((unsigned)f2bf(acc[3]) << 16));
  o.z = (int)((unsigned)f2bf(acc[4]) | ((unsigned)f2bf(acc[5]) << 16));
  o.w = (int)((unsigned)f2bf(acc[6]) | ((unsigned)f2bf(acc[7]) << 16));
  *(int4*)(ob + i) = o;
}

extern "C" void kernel_launch(void* const* d_in, const int* in_sizes, int n_in,
                              void* d_out, int out_size, void* d_ws, size_t ws_size,
                              hipStream_t stream) {
  const float* x  = (const float*)d_in[0];
  const float* st = (const float*)d_in[1];
  const float* Aw = (const float*)d_in[2];
  const float* Ab = (const float*)d_in[3];
  const float* Bw = (const float*)d_in[4];
  const float* Bb = (const float*)d_in[5];
  const float* Cw = (const float*)d_in[6];
  const float* Cb = (const float*)d_in[7];
  const float* Dw = (const float*)d_in[8];
  const float* Db = (const float*)d_in[9];
  const float* Iw = (const float*)d_in[10];
  const float* Ib = (const float*)d_in[11];
  const float* Sw = (const float*)d_in[12];
  const float* Sb = (const float*)d_in[13];
  const float* Ow = (const float*)d_in[14];

  float* y = (float*)d_out;                               // [T][B][C]
  float* state_out = y + (size_t)T_DIM * B_DIM * C_DIM;   // [B][F][F]

  // workspace carve:
  //   Wall      @ 0           (1,572,864)
  //   biasAll   @ 1,572,864   (3,072, padded)
  //   Owb       @ 1,576,960   (262,144)
  //   P         @ 1,839,104   (100,663,296)
  //   ob        @ 102,502,400 (8,388,608)
  //   xb        @ 110,891,008 (67,108,864)  -- dead after proj GEMM
  //   o_part    @ 110,891,008 (G * 8,388,608) reuses xb region; G=16 extends past it
  char* ws = (char*)d_ws;
  unsigned short* Wall = (unsigned short*)(ws);
  float* biasAll       = (float*)(ws + 1572864);
  unsigned short* Owb  = (unsigned short*)(ws + 1576960);
  float* P             = (float*)(ws + 1839104);
  unsigned short* ob   = (unsigned short*)(ws + 102502400);
  unsigned short* xb   = (unsigned short*)(ws + 110891008);
  unsigned short* o_part = xb;

  // G=16 wants 110,891,008 + 16*8,388,608 = 245,108,736 bytes of ws
  const int G = (ws_size >= 245108736u) ? 16 : 8;

  cvt_kernel<<<4096, 256, 0, stream>>>(x, xb, 33554432 / 4);
  pack_w_kernel<<<3072, 256, 0, stream>>>(Aw, Ab, Bw, Bb, Cw, Cb, Dw, Db, Iw, Ib, Sw, Sb,
                                          Wall, biasAll);
  cvt_kernel<<<128, 256, 0, stream>>>(Ow, Owb, 131072 / 4);
  // projections: P = x @ Wall^T + bias, sigmoid on I-slot cols [512,640)
  gemm_bt<<<dim3(256, 6), 256, 0, stream>>>(xb, Wall, P, biasAll, 32768, 768, 1024, 512, 640);
  if (G == 16)
    scan_kernel<2><<<dim3(8, 16), 256, 0, stream>>>(P, st, o_part, state_out);
  else
    scan_kernel<4><<<dim3(8, 8), 256, 0, stream>>>(P, st, o_part, state_out);
  reduce_kernel<<<2048, 256, 0, stream>>>(o_part, ob, G);
  // y = o @ O_w^T
  gemm_bt<<<dim3(256, 8), 256, 0, stream>>>(ob, Owb, y, nullptr, 32768, 1024, 128, 0, 0);
}

// Round 5
// 1094.549 us; speedup vs baseline: 1.2104x; 1.0380x over previous
//
#include <hip/hip_runtime.h>

// DeltanetHead: T=4096, B=8, C=1024, F=128
// R8: occupancy fix for the latency-bound scan. R7 evidence: 453 cyc/step,
// VALUBusy 14% (only ~65 cyc of issue), Occupancy 6% = 1 wave/SIMD -- every
// dependent-latency bubble (DPP chain, lgkm waits) is exposed wall-clock.
// Fix: 512-thread blocks (8 waves, ROWS=1/wave), grid (8,16). Each CU now
// holds 8 waves = 2 INDEPENDENT scan chains per SIMD, so one wave's compute
// fills the other's stalls. P staging DMA shared by 8 waves (3 chunks each);
// per-wave step shrinks to ~28 instrs (one DPP chain).

#define T_DIM 4096
#define B_DIM 8
#define C_DIM 1024
#define F_DIM 128

typedef __attribute__((ext_vector_type(8))) short bf16x8;
typedef __attribute__((ext_vector_type(4))) float f32x4;

__device__ __forceinline__ unsigned short f2bf(float f) {
  unsigned u = __float_as_uint(f);
  u += 0x7fffu + ((u >> 16) & 1u);   // round-to-nearest-even
  return (unsigned short)(u >> 16);
}
__device__ __forceinline__ float bfu2f(unsigned u) { return __uint_as_float(u << 16); }

__device__ __forceinline__ void gload_lds16(const float* g, float* l) {
  __builtin_amdgcn_global_load_lds((const __attribute__((address_space(1))) void*)g,
                                   (__attribute__((address_space(3))) void*)l, 16, 0, 0);
}

// ---------------- elementwise fp32 -> bf16 convert (vectorized x4) ----------------
__global__ void cvt_kernel(const float* __restrict__ in, unsigned short* __restrict__ out, int n4) {
  int i = blockIdx.x * blockDim.x + threadIdx.x;
  int stride = gridDim.x * blockDim.x;
  for (; i < n4; i += stride) {
    float4 v = ((const float4*)in)[i];
    ushort4 r;
    r.x = f2bf(v.x); r.y = f2bf(v.y); r.z = f2bf(v.z); r.w = f2bf(v.w);
    ((ushort4*)out)[i] = r;
  }
}

// ---------------- pack 6 [F][C] weights -> Wall[768][1024] bf16 + bias[768] ----------------
__global__ void pack_w_kernel(const float* __restrict__ Aw, const float* __restrict__ Ab,
                              const float* __restrict__ Bw, const float* __restrict__ Bb,
                              const float* __restrict__ Cw, const float* __restrict__ Cb,
                              const float* __restrict__ Dw, const float* __restrict__ Db,
                              const float* __restrict__ Iw, const float* __restrict__ Ib,
                              const float* __restrict__ Sw, const float* __restrict__ Sb,
                              unsigned short* __restrict__ Wall, float* __restrict__ biasAll) {
  const float scaleB = 0.08838834764831845f;  // 1/sqrt(128), folded into b-projection
  int idx = blockIdx.x * 256 + threadIdx.x;
  if (idx < 768 * 1024) {
    int row = idx >> 10, c = idx & 1023;
    int slot = row >> 7, rr = row & 127;
    const float* W = slot == 0 ? Aw : slot == 1 ? Bw : slot == 2 ? Cw
                   : slot == 3 ? Dw : slot == 4 ? Iw : Sw;
    float v = W[rr * 1024 + c];
    if (slot == 1) v *= scaleB;
    Wall[idx] = f2bf(v);
  }
  if (idx < 768) {
    int slot = idx >> 7, rr = idx & 127;
    const float* Bv = slot == 0 ? Ab : slot == 1 ? Bb : slot == 2 ? Cb
                    : slot == 3 ? Db : slot == 4 ? Ib : Sb;
    float v = Bv[rr];
    if (slot == 1) v *= scaleB;
    biasAll[idx] = v;
  }
}

// ---------------- bf16 MFMA GEMM: C[M][N] = A[M][K] * B[N][K]^T (+bias, +sigmoid range) ----------------
__global__ __launch_bounds__(256) void gemm_bt(
    const unsigned short* __restrict__ A,
    const unsigned short* __restrict__ Bm,
    float* __restrict__ Cm,
    const float* __restrict__ bias,
    int M, int N, int K, int sig_lo, int sig_hi) {
  __shared__ unsigned short As[128 * 32];
  __shared__ unsigned short Bs[128 * 32];
  const int tid = threadIdx.x;
  const int m0 = blockIdx.x * 128;
  const int n0 = blockIdx.y * 128;
  const int wv = tid >> 6, ln = tid & 63;
  const int mo = (wv & 1) * 64, no = (wv >> 1) * 64;
  const int lrow = ln & 15, lq = ln >> 4;
  f32x4 acc[4][4] = {};

  for (int kt = 0; kt < K; kt += 32) {
#pragma unroll
    for (int it = 0; it < 2; ++it) {
      int idx = it * 256 + tid;
      int row = idx >> 2, kc = idx & 3;
      *(int4*)&As[row * 32 + kc * 8] = *(const int4*)&A[(size_t)(m0 + row) * K + kt + kc * 8];
      *(int4*)&Bs[row * 32 + kc * 8] = *(const int4*)&Bm[(size_t)(n0 + row) * K + kt + kc * 8];
    }
    __syncthreads();
    bf16x8 af[4], bf[4];
#pragma unroll
    for (int i = 0; i < 4; ++i) {
      af[i] = *(const bf16x8*)&As[(mo + i * 16 + lrow) * 32 + lq * 8];
      bf[i] = *(const bf16x8*)&Bs[(no + i * 16 + lrow) * 32 + lq * 8];
    }
#pragma unroll
    for (int i = 0; i < 4; ++i)
#pragma unroll
      for (int j = 0; j < 4; ++j)
        acc[i][j] = __builtin_amdgcn_mfma_f32_16x16x32_bf16(af[i], bf[j], acc[i][j], 0, 0, 0);
    __syncthreads();
  }

#pragma unroll
  for (int i = 0; i < 4; ++i) {
#pragma unroll
    for (int j = 0; j < 4; ++j) {
      int col = n0 + no + j * 16 + lrow;
      float bv = bias ? bias[col] : 0.0f;
      bool sig = (col >= sig_lo) && (col < sig_hi);
#pragma unroll
      for (int r = 0; r < 4; ++r) {
        int row = m0 + mo + i * 16 + lq * 4 + r;
        float v = acc[i][j][r] + bv;
        if (sig) v = 1.0f / (1.0f + __expf(-v));
        Cm[(size_t)row * N + col] = v;
      }
    }
  }
}

// ---------------- wave-wide sum via DPP ----------------
__device__ __forceinline__ float wave_sum64(float x) {
  x += __int_as_float(__builtin_amdgcn_update_dpp(0, __float_as_int(x), 0x111, 0xf, 0xf, false)); // row_shr:1
  x += __int_as_float(__builtin_amdgcn_update_dpp(0, __float_as_int(x), 0x112, 0xf, 0xf, false)); // row_shr:2
  x += __int_as_float(__builtin_amdgcn_update_dpp(0, __float_as_int(x), 0x114, 0xf, 0xf, false)); // row_shr:4
  x += __int_as_float(__builtin_amdgcn_update_dpp(0, __float_as_int(x), 0x118, 0xf, 0xf, false)); // row_shr:8
  x += __int_as_float(__builtin_amdgcn_update_dpp(0, __float_as_int(x), 0x142, 0xf, 0xf, false)); // row_bcast:15
  x += __int_as_float(__builtin_amdgcn_update_dpp(0, __float_as_int(x), 0x143, 0xf, 0xf, false)); // row_bcast:31
  return __int_as_float(__builtin_amdgcn_readlane(__float_as_int(x), 63));
}

// ---------------- sequential scan ----------------
// grid (B, G), 512 thr (8 waves). Wave owns ROWS rows, lane owns 2 cols.
// 8 waves/CU = 2 independent chains per SIMD (latency hiding). P staged
// batch-by-batch into LDS via global_load_lds (double-buffered, waited once
// per batch); per-step operands ds_read from LDS with 1-step register
// prefetch. Cross-wave reduce once per 8 steps (parity dbuf, one barrier).
template <int ROWS>
__global__ __launch_bounds__(512, 2) void scan_kernel(
    const float* __restrict__ P,          // [T][B][6][128] fp32
    const float* __restrict__ state_in,   // [B][128][128]
    unsigned short* __restrict__ o_part,  // [G][T][B][128] bf16
    float* __restrict__ state_out) {      // [B][128][128]
  const int b = blockIdx.x;
  const int gq = blockIdx.y;
  const int wave = threadIdx.x >> 6;      // 0..7
  const int lane = threadIdx.x & 63;
  const int r0 = gq * (8 * ROWS) + wave * ROWS;
  const int j0 = lane * 2;
  __shared__ float stage[2][8][768];      // 48 KB: [buf][step][768] P rows
  __shared__ float buf[2][8][8][128];     // 64 KB: [parity][wave][step][col]

  float2 st[ROWS];
#pragma unroll
  for (int r = 0; r < ROWS; ++r)
    st[r] = *(const float2*)&state_in[((size_t)b * F_DIM + r0 + r) * F_DIM + j0];

  // stage one 8-step batch starting at tstart into stage[sb]:
  // wave w DMAs step w's 3 KB as 3 chunks of 1024 B (64 lanes x 16 B).
  // tail batches overrun past P's end into the adjacent allocated ob
  // region (staged but never consumed).
  auto stage_batch = [&](int sb, int tstart) {
#pragma unroll
    for (int part = 0; part < 3; ++part) {
      const float* g = P + ((size_t)(tstart + wave) * B_DIM + b) * 768 + part * 256 + lane * 4;
      gload_lds16(g, &stage[sb][wave][part * 256]);
    }
  };

#define LDS_STEP(da, db, dd, dg, dc, ds, sb, kk)                             \
  do {                                                                       \
    const float* Sp = &stage[sb][kk][0];                                     \
    da = *(const float2*)(Sp + 0 + j0);                                      \
    db = *(const float2*)(Sp + 128 + j0);                                    \
    dd = *(const float2*)(Sp + 384 + j0);                                    \
    dg = *(const float2*)(Sp + 512 + j0);                                    \
    if constexpr (ROWS == 1) {                                               \
      dc[0] = *(Sp + 256 + r0);                                              \
      ds[0] = *(Sp + 640 + r0);                                              \
    } else {                                                                 \
      float2 v_ = *(const float2*)(Sp + 256 + r0);                           \
      dc[0] = v_.x; dc[1] = v_.y;                                            \
      float2 w_ = *(const float2*)(Sp + 640 + r0);                           \
      ds[0] = w_.x; ds[1] = w_.y;                                            \
    }                                                                        \
  } while (0)

  // prologue: stage batch 0, wait own DMA, sync (=> all waves' DMA done)
  stage_batch(0, 0);
  asm volatile("s_waitcnt vmcnt(0)" ::: "memory");
  __builtin_amdgcn_s_barrier();
  asm volatile("" ::: "memory");

  int cur = 0;
  for (int t8 = 0; t8 < T_DIM; t8 += 8) {
    const int pb = (t8 >> 3) & 1;
    // issue DMA for the next batch into the other stage buffer (waited at
    // this batch's end-of-batch vmcnt(0) -- ~8 steps of slack)
    stage_batch(cur ^ 1, t8 + 8);

    // 1-step register prefetch out of LDS
    float2 a2, b2, d2, g2;
    float cc[ROWS], ss[ROWS];
    LDS_STEP(a2, b2, d2, g2, cc, ss, cur, 0);

#pragma unroll
    for (int k = 0; k < 8; ++k) {
      float2 ca = a2, cb = b2, cd = d2, cg = g2;
      float lc[ROWS], ls[ROWS];
#pragma unroll
      for (int r = 0; r < ROWS; ++r) { lc[r] = cc[r]; ls[r] = ss[r]; }
      if (k < 7) LDS_STEP(a2, b2, d2, g2, cc, ss, cur, k + 1);

      // v[r] = st[r,:] . a  (old state, wave-wide reduce over 128 cols)
      float vr[ROWS];
#pragma unroll
      for (int r = 0; r < ROWS; ++r)
        vr[r] = wave_sum64(st[r].x * ca.x + st[r].y * ca.y);

      // st update + partial out over this wave's rows
      float ox = 0.0f, oy = 0.0f;
#pragma unroll
      for (int r = 0; r < ROWS; ++r) {
        st[r].x = st[r].x * cg.x + vr[r] * cb.x + lc[r] * cd.x;
        st[r].y = st[r].y * cg.y + vr[r] * cb.y + lc[r] * cd.y;
        ox += ls[r] * st[r].x;
        oy += ls[r] * st[r].y;
      }
      *(float2*)&buf[pb][wave][k][j0] = make_float2(ox, oy);
      // keep the k+1 LDS reads inside this step's region
      __builtin_amdgcn_sched_barrier(0);
    }

    // end-of-batch: wait own staging DMA (vmcnt) + all LDS ops (lgkm), sync.
    asm volatile("s_waitcnt vmcnt(0) lgkmcnt(0)" ::: "memory");
    __builtin_amdgcn_s_barrier();
    asm volatile("" ::: "memory");

    // cross-wave reduce of the 8-step batch: 512 thr x 1 col-pair each
    {
      int k = threadIdx.x >> 6;          // 0..7
      int c2 = (threadIdx.x & 63) * 2;
      float sx = 0.0f, sy = 0.0f;
#pragma unroll
      for (int w = 0; w < 8; ++w) {
        float2 v = *(const float2*)&buf[pb][w][k][c2];
        sx += v.x; sy += v.y;
      }
      unsigned pk = (unsigned)f2bf(sx) | ((unsigned)f2bf(sy) << 16);
      *(unsigned*)&o_part[(((size_t)gq * T_DIM + t8 + k) * B_DIM + b) * F_DIM + c2] = pk;
    }
    // no second barrier: parity double-buffer + the next batch's barrier
    // orders buf reuse; stage reuse is ordered by the lgkmcnt(0)+barrier.
    cur ^= 1;
  }
#undef LDS_STEP

#pragma unroll
  for (int r = 0; r < ROWS; ++r)
    *(float2*)&state_out[((size_t)b * F_DIM + r0 + r) * F_DIM + j0] = st[r];
}

// ---------------- sum G bf16 partials -> ob bf16 (memory-bound) ----------------
__global__ void reduce_kernel(const unsigned short* __restrict__ o_part,
                              unsigned short* __restrict__ ob, int G) {
  const size_t NEL = (size_t)T_DIM * B_DIM * F_DIM;  // 4,194,304
  size_t i = ((size_t)blockIdx.x * 256 + threadIdx.x) * 8;
  if (i >= NEL) return;
  float acc[8] = {0, 0, 0, 0, 0, 0, 0, 0};
  for (int g = 0; g < G; ++g) {
    int4 v = *(const int4*)(o_part + (size_t)g * NEL + i);
    unsigned w0 = (unsigned)v.x, w1 = (unsigned)v.y, w2 = (unsigned)v.z, w3 = (unsigned)v.w;
    acc[0] += bfu2f(w0 & 0xffffu); acc[1] += bfu2f(w0 >> 16);
    acc[2] += bfu2f(w1 & 0xffffu); acc[3] += bfu2f(w1 >> 16);
    acc[4] += bfu2f(w2 & 0xffffu); acc[5] += bfu2f(w2 >> 16);
    acc[6] += bfu2f(w3 & 0xffffu); acc[7] += bfu2f(w3 >> 16);
  }
  int4 o;
  o.x = (int)((unsigned)f2bf(acc[0]) | ((unsigned)f2bf(acc[1]) << 16));
  o.y = (int)((unsigned)f2bf(acc[2]) | ((unsigned)f2bf(acc[3]) << 16));
  o.z = (int)((unsigned)f2bf(acc[4]) | ((unsigned)f2bf(acc[5]) << 16));
  o.w = (int)((unsigned)f2bf(acc[6]) | ((unsigned)f2bf(acc[7]) << 16));
  *(int4*)(ob + i) = o;
}

extern "C" void kernel_launch(void* const* d_in, const int* in_sizes, int n_in,
                              void* d_out, int out_size, void* d_ws, size_t ws_size,
                              hipStream_t stream) {
  const float* x  = (const float*)d_in[0];
  const float* st = (const float*)d_in[1];
  const float* Aw = (const float*)d_in[2];
  const float* Ab = (const float*)d_in[3];
  const float* Bw = (const float*)d_in[4];
  const float* Bb = (const float*)d_in[5];
  const float* Cw = (const float*)d_in[6];
  const float* Cb = (const float*)d_in[7];
  const float* Dw = (const float*)d_in[8];
  const float* Db = (const float*)d_in[9];
  const float* Iw = (const float*)d_in[10];
  const float* Ib = (const float*)d_in[11];
  const float* Sw = (const float*)d_in[12];
  const float* Sb = (const float*)d_in[13];
  const float* Ow = (const float*)d_in[14];

  float* y = (float*)d_out;                               // [T][B][C]
  float* state_out = y + (size_t)T_DIM * B_DIM * C_DIM;   // [B][F][F]

  // workspace carve:
  //   Wall      @ 0           (1,572,864)
  //   biasAll   @ 1,572,864   (3,072, padded)
  //   Owb       @ 1,576,960   (262,144)
  //   P         @ 1,839,104   (100,663,296)
  //   ob        @ 102,502,400 (8,388,608)
  //   xb        @ 110,891,008 (67,108,864)  -- dead after proj GEMM
  //   o_part    @ 110,891,008 (G * 8,388,608) reuses xb region; G=16 extends past it
  char* ws = (char*)d_ws;
  unsigned short* Wall = (unsigned short*)(ws);
  float* biasAll       = (float*)(ws + 1572864);
  unsigned short* Owb  = (unsigned short*)(ws + 1576960);
  float* P             = (float*)(ws + 1839104);
  unsigned short* ob   = (unsigned short*)(ws + 102502400);
  unsigned short* xb   = (unsigned short*)(ws + 110891008);
  unsigned short* o_part = xb;

  // G=16 wants 110,891,008 + 16*8,388,608 = 245,108,736 bytes of ws
  const int G = (ws_size >= 245108736u) ? 16 : 8;

  cvt_kernel<<<4096, 256, 0, stream>>>(x, xb, 33554432 / 4);
  pack_w_kernel<<<3072, 256, 0, stream>>>(Aw, Ab, Bw, Bb, Cw, Cb, Dw, Db, Iw, Ib, Sw, Sb,
                                          Wall, biasAll);
  cvt_kernel<<<128, 256, 0, stream>>>(Ow, Owb, 131072 / 4);
  // projections: P = x @ Wall^T + bias, sigmoid on I-slot cols [512,640)
  gemm_bt<<<dim3(256, 6), 256, 0, stream>>>(xb, Wall, P, biasAll, 32768, 768, 1024, 512, 640);
  if (G == 16)
    scan_kernel<1><<<dim3(8, 16), 512, 0, stream>>>(P, st, o_part, state_out);
  else
    scan_kernel<2><<<dim3(8, 8), 512, 0, stream>>>(P, st, o_part, state_out);
  reduce_kernel<<<2048, 256, 0, stream>>>(o_part, ob, G);
  // y = o @ O_w^T
  gemm_bt<<<dim3(256, 8), 256, 0, stream>>>(ob, Owb, y, nullptr, 32768, 1024, 128, 0, 0);
}